// Round 15
// baseline (89.669 us; speedup 1.0000x reference)
//
#include <hip/hip_runtime.h>
#include <hip/hip_fp16.h>
#include <math.h>

#define BB 64
#define TT 2000
#define VV 128
#define SS 100
#define NP 1000            // row-pairs per batch: pair p holds frames 2p+1, 2p+2
#define PRB 448            // bytes per pair-row: 56 lanes * 8B = exactly 7 cache lines
#define LN2D 0.6931471805599453

typedef double v2d __attribute__((ext_vector_type(2)));

// wave-wide f32 sum via DPP; result uniform via readlane
__device__ __forceinline__ float wave_sum_f32(float v) {
    int t;
    t = __builtin_amdgcn_update_dpp(0, __float_as_int(v), 0x111, 0xF, 0xF, true);  v += __int_as_float(t);
    t = __builtin_amdgcn_update_dpp(0, __float_as_int(v), 0x112, 0xF, 0xF, true);  v += __int_as_float(t);
    t = __builtin_amdgcn_update_dpp(0, __float_as_int(v), 0x114, 0xF, 0xF, true);  v += __int_as_float(t);
    t = __builtin_amdgcn_update_dpp(0, __float_as_int(v), 0x118, 0xF, 0xF, true);  v += __int_as_float(t);
    t = __builtin_amdgcn_update_dpp(0, __float_as_int(v), 0x142, 0xA, 0xF, false); v += __int_as_float(t);
    t = __builtin_amdgcn_update_dpp(0, __float_as_int(v), 0x143, 0xC, 0xF, false); v += __int_as_float(t);
    return __int_as_float(__builtin_amdgcn_readlane(__float_as_int(v), 63));
}

// per-half sums: sA = sum lanes 0..31, sB = sum lanes 32..63
__device__ __forceinline__ void half_sums_f32(float v, float* sA, float* sB) {
    int t;
    t = __builtin_amdgcn_update_dpp(0, __float_as_int(v), 0x111, 0xF, 0xF, true);  v += __int_as_float(t);
    t = __builtin_amdgcn_update_dpp(0, __float_as_int(v), 0x112, 0xF, 0xF, true);  v += __int_as_float(t);
    t = __builtin_amdgcn_update_dpp(0, __float_as_int(v), 0x114, 0xF, 0xF, true);  v += __int_as_float(t);
    t = __builtin_amdgcn_update_dpp(0, __float_as_int(v), 0x118, 0xF, 0xF, true);  v += __int_as_float(t);
    t = __builtin_amdgcn_update_dpp(0, __float_as_int(v), 0x142, 0xA, 0xF, false); v += __int_as_float(t); // bcast15
    *sA = __int_as_float(__builtin_amdgcn_readlane(__float_as_int(v), 31));
    *sB = __int_as_float(__builtin_amdgcn_readlane(__float_as_int(v), 63));
}

// ---------------- Kernel 1: blank-normalized label probs (round-12 form, measured ~18us) ----------------
__global__ __launch_bounds__(256) void ctc_k1(
    const float* __restrict__ logits, const int* __restrict__ targets,
    const int* __restrict__ in_lens, ushort* __restrict__ pe2,
    float* __restrict__ logSb, float* __restrict__ out)
{
    if (blockIdx.x == 0 && threadIdx.x == 0) out[0] = 0.f;   // k1 completes before k2 starts
    const int wv = threadIdx.x >> 6, lane = threadIdx.x & 63;
    const int gp = blockIdx.x * 4 + wv;          // 0 .. BB*NP-1
    const int b = gp / NP, p = gp - b * NP;
    const int n = in_lens[b];
    if (p > ((n - 2) >> 1)) return;              // dead pair: frames >= n are frozen
    const int tA = 2 * p + 1, tB = 2 * p + 2;
    const bool vB = (tB < TT);

    const int trow = (lane < 32) ? tA : (vB ? tB : tA);
    float4 x4 = reinterpret_cast<const float4*>(logits + ((size_t)b * TT + trow) * VV)[lane & 31];

    float e0 = __expf(x4.x), e1 = __expf(x4.y);
    float e2 = __expf(x4.z), e3 = __expf(x4.w);
    float sa, sb;
    half_sums_f32((e0 + e1) + (e2 + e3), &sa, &sb);

    __shared__ float sm[4][2][VV];
    {
        float4 ev; ev.x = e0; ev.y = e1; ev.z = e2; ev.w = e3;
        *reinterpret_cast<float4*>(&sm[wv][lane >> 5][(lane & 31) * 4]) = ev;
    }
    // producer and consumer are the SAME wave: no barrier needed

    int tg0 = 0, tg1 = 0;
    if (lane < 50) {
        int2 tg = reinterpret_cast<const int2*>(targets)[b * (SS / 2) + lane];
        tg0 = tg.x; tg1 = tg.y;
    }
    const float qiA = 1.0f / sm[wv][0][0];
    const float qiB = 1.0f / sm[wv][1][0];
    float q1a = 0.f, q3a = 0.f, q1b = 0.f, q3b = 0.f;
    if (lane < 50) {                                  // slots 4l+1, 4l+3 <= 199 < 201
        q1a = fminf(sm[wv][0][tg0] * qiA, 65504.f);
        q3a = fminf(sm[wv][0][tg1] * qiA, 65504.f);
        if (vB) {
            q1b = fminf(sm[wv][1][tg0] * qiB, 65504.f);
            q3b = fminf(sm[wv][1][tg1] * qiB, 65504.f);
        }
    }
    if (lane < 56) {                                  // full 7-line row, zero padded
        ushort4 w;
        w.x = __half_as_ushort(__float2half_rn(q1a));
        w.y = __half_as_ushort(__float2half_rn(q3a));
        w.z = __half_as_ushort(__float2half_rn(q1b));
        w.w = __half_as_ushort(__float2half_rn(q3b));
        *reinterpret_cast<ushort4*>((char*)pe2 + ((size_t)b * NP + p) * PRB + lane * 8) = w;
    }
    if (lane == 0) {
        float xB0 = __int_as_float(__builtin_amdgcn_readlane(__float_as_int(x4.x), 32));
        logSb[b * TT + tA] = __logf(sa) - x4.x;
        if (vB) logSb[b * TT + tB] = __logf(sb) - xB0;
    }
}

// ---------------- Kernel 2: bidirectional scan, 4 batches (8 waves) per block ----------------
// 2 independent chains per SIMD hide each other's f64 dependence latency.
union H4 { uint2 u; __half h[4]; };

__device__ __forceinline__ double dpp_shr1_f64(double x) {   // lane l <- l-1, lane0 -> 0
    long long bl = __double_as_longlong(x);
    int lo = (int)bl, hi = (int)(bl >> 32);
    lo = __builtin_amdgcn_update_dpp(0, lo, 0x138, 0xF, 0xF, true);  // wave_shr:1
    hi = __builtin_amdgcn_update_dpp(0, hi, 0x138, 0xF, 0xF, true);
    return __longlong_as_double((long long)(((unsigned long long)(unsigned)hi << 32) | (unsigned)lo));
}

__device__ __forceinline__ double dpp_shl1_f64(double x) {   // lane l <- l+1, lane63 -> 0
    long long bl = __double_as_longlong(x);
    int lo = (int)bl, hi = (int)(bl >> 32);
    lo = __builtin_amdgcn_update_dpp(0, lo, 0x130, 0xF, 0xF, true);  // wave_shl:1
    hi = __builtin_amdgcn_update_dpp(0, hi, 0x130, 0xF, 0xF, true);
    return __longlong_as_double((long long)(((unsigned long long)(unsigned)hi << 32) | (unsigned)lo));
}

__device__ __forceinline__ int wave_max_i32(int v) {
    int t;
    t = __builtin_amdgcn_update_dpp(0, v, 0x111, 0xF, 0xF, true); v = v > t ? v : t;
    t = __builtin_amdgcn_update_dpp(0, v, 0x112, 0xF, 0xF, true); v = v > t ? v : t;
    t = __builtin_amdgcn_update_dpp(0, v, 0x114, 0xF, 0xF, true); v = v > t ? v : t;
    t = __builtin_amdgcn_update_dpp(0, v, 0x118, 0xF, 0xF, true); v = v > t ? v : t;
    t = __builtin_amdgcn_update_dpp(v, v, 0x142, 0xA, 0xF, false); v = v > t ? v : t;
    t = __builtin_amdgcn_update_dpp(v, v, 0x143, 0xC, 0xF, false); v = v > t ? v : t;
    return __builtin_amdgcn_readlane(v, 63);
}

// state d02=(a0,a2), d13=(a1,a3); per frame: 4 packed f64 ops + 1 f64 DPP shift.
#define FSTEPV(QV) do {                                      \
    double am1 = dpp_shr1_f64(d13.y);                        \
    v2d m; m.x = am1; m.y = d13.x;                           \
    v2d t = d02 + d13;            /* (a0+a1, a2+a3) */       \
    v2d u = skv * m + t;          /* (+sk1*am1, +sk3*a1) */  \
    d02 = d02 + m;                /* (a0+am1, a1+a2) */      \
    d13 = u * (QV);                                          \
} while (0)

// bwd state d02=(b0,b2), d13=(b1,b3)
#define BSTEPV(QV) do {                                      \
    double bp0 = dpp_shl1_f64(d02.x);                        \
    double bp1 = dpp_shl1_f64(d13.x);                        \
    v2d s2; s2.x = d02.y; s2.y = bp0;                        \
    v2d m;  m.x = d13.y;  m.y = bp1;                         \
    v2d t = d13 + s2;             /* (b1+b2, b3+bp0) */      \
    v2d u = skvB * m + t;         /* (+sk3*b3, +skB*bp1) */  \
    d02 = d02 + d13;              /* (b0+b1, b2+b3) */       \
    d13 = u * (QV);                                          \
} while (0)

#define RENORMV() do {                                       \
    int h0 = (int)(__double_as_longlong(d02.x) >> 32);       \
    int h1 = (int)(__double_as_longlong(d13.x) >> 32);       \
    int h2 = (int)(__double_as_longlong(d02.y) >> 32);       \
    int h3 = (int)(__double_as_longlong(d13.y) >> 32);       \
    int m01 = h0 > h1 ? h0 : h1;                             \
    int m23 = h2 > h3 ? h2 : h3;                             \
    int mm  = wave_max_i32(m01 > m23 ? m01 : m23);           \
    int ex  = (mm >> 20) & 0x7FF;                            \
    int exc = ex > 0 ? ex : 1;                               \
    double f = __longlong_as_double((long long)(2046 - exc) << 52); \
    v2d fv; fv.x = f; fv.y = f;                              \
    d02 *= fv; d13 *= fv;                                    \
    Epow += exc - 1023;                                      \
} while (0)

#define CVTP(H, QA, QB) do {                                 \
    (QA).x = (double)__half2float((H).h[0]);                 \
    (QA).y = (double)__half2float((H).h[1]);                 \
    (QB).x = (double)__half2float((H).h[2]);                 \
    (QB).y = (double)__half2float((H).h[3]); } while (0)

__global__ __launch_bounds__(512) void ctc_k2(
    const float* __restrict__ logits, const ushort* __restrict__ pe2,
    const float* __restrict__ logSb, const int* __restrict__ targets,
    const int* __restrict__ in_lens, const int* __restrict__ tgt_lens,
    float* __restrict__ out)
{
    const int tid  = threadIdx.x;
    const int sub  = tid >> 7;          // 0..3: batch slot within block
    const int b    = blockIdx.x * 4 + sub;
    const int wv   = (tid >> 6) & 1;    // 0 = forward (alpha), 1 = backward (beta)
    const int lane = tid & 63;
    const int ltid = tid & 127;         // thread id within this batch's 2 waves
    const int n    = in_lens[b];
    const int tl   = tgt_lens[b];

    const int P  = (13 * (n - 2)) / 50;     // forward pairs (frames 1..2P)
    const int pL = (n - 2) >> 1;            // pair containing frame n-1

    __shared__ double SA[4][256];
    __shared__ double SC[4][256];
    __shared__ double sred[4][2];
    __shared__ int    sE[4][2];

    int tg0 = 0, tg1 = 0, tgm1 = 0, tg2 = 0;
    if (lane < 50) {
        int2 tg = reinterpret_cast<const int2*>(targets)[b * (SS / 2) + lane];
        tg0 = tg.x; tg1 = tg.y;
    }
    if (lane >= 1 && lane <= 50) tgm1 = targets[b * SS + 2 * lane - 1];
    if (lane <= 48) tg2 = targets[b * SS + 2 * lane + 2];
    const double sk1 = (tg0 != tgm1) ? 1.0 : 0.0;   // fwd: slot 4l+1 <- 4l-1
    const double sk3 = (tg1 != tg0)  ? 1.0 : 0.0;   // fwd: 4l+3 <- 4l+1; bwd: 4l+1 <- 4l+3
    const double skB = (tg2 != tg1)  ? 1.0 : 0.0;   // bwd: slot 4l+3 <- 4l+5
    v2d skv;  skv.x  = sk1; skv.y  = sk3;
    v2d skvB; skvB.x = sk3; skvB.y = skB;

    const int cl = (lane < 51) ? lane : 50;
    const char* PBbase = (const char*)pe2 + (size_t)b * NP * PRB + (size_t)cl * 8;

    v2d d02; d02.x = 0.0; d02.y = 0.0;
    v2d d13; d13.x = 0.0; d13.y = 0.0;
    int Epow = 0;
    double lsb0 = 0.0;
    uint2 buf[16];

    if (wv == 0) {
        // frame-0 prologue from logits
        float2 x0 = reinterpret_cast<const float2*>(logits + (size_t)b * TT * VV)[lane];
        float e00 = __expf(x0.x), e01 = __expf(x0.y);
        float s0v = wave_sum_f32(e00 + e01);
        float qb0 = __shfl(e00, 0);
        int ext1 = targets[b * SS];                      // first label (uniform)
        float qn = __shfl((ext1 & 1) ? e01 : e00, ext1 >> 1);
        if (lane == 0) {
            d02.x = 1.0;
            if (tl > 0) d13.x = (double)qn / (double)qb0;
            lsb0 = (double)__logf(s0v) - (double)x0.x;
        }

        // forward pairs 0 .. P-1 (frames 1..2P), cvt pipelined 1 pair ahead
        #pragma unroll
        for (int d = 0; d < 16; ++d)
            buf[d] = *reinterpret_cast<const uint2*>(PBbase + (size_t)d * PRB);
        const char* Pc = PBbase + (size_t)16 * PRB;
        v2d cA, cB, nA, nB;
        { H4 h0; h0.u = buf[0]; CVTP(h0, cA, cB); }
        const int nfull = P >> 4, rem = P & 15;
        for (int c = 0; c < nfull; ++c) {
            #pragma unroll
            for (int d = 0; d < 16; ++d) {
                H4 hn; hn.u = buf[(d + 1) & 15];
                buf[d] = *reinterpret_cast<const uint2*>(Pc + (size_t)d * PRB);
                CVTP(hn, nA, nB);
                FSTEPV(cA);
                FSTEPV(cB);
                cA = nA; cB = nB;
            }
            RENORMV();
            Pc += (size_t)16 * PRB;
        }
        #pragma unroll
        for (int d = 0; d < 16; ++d) {
            if (d < rem) {
                H4 h; h.u = buf[d];
                v2d qA, qB; CVTP(h, qA, qB);
                FSTEPV(qA);
                FSTEPV(qB);
            }
        }
        RENORMV();
        SA[sub][4 * lane + 0] = d02.x; SA[sub][4 * lane + 1] = d13.x;
        SA[sub][4 * lane + 2] = d02.y; SA[sub][4 * lane + 3] = d13.y;
        if (lane == 0) sE[sub][0] = Epow;
    } else {
        // backward init at frame n-1 (from pair pL)
        H4 hi; hi.u = *reinterpret_cast<const uint2*>(PBbase + (size_t)pL * PRB);
        const bool nOdd = (n & 1);
        double q1i = (double)__half2float(nOdd ? hi.h[2] : hi.h[0]);
        double q3i = (double)__half2float(nOdd ? hi.h[3] : hi.h[1]);
        const int s2i = 2 * tl, s1i = 2 * tl - 1;
        d02.x = (4 * lane     == s2i) ? 1.0 : 0.0;
        d13.x = (4 * lane + 1 == s1i) ? q1i : 0.0;
        d02.y = (4 * lane + 2 == s2i) ? 1.0 : 0.0;
        d13.y = (4 * lane + 3 == s1i) ? q3i : 0.0;
        if (nOdd) {   // extra step for frame n-2 = tA of pair pL
            v2d qv; qv.x = (double)__half2float(hi.h[0]); qv.y = (double)__half2float(hi.h[1]);
            BSTEPV(qv);
        }

        const int NB = pL - P;
        #pragma unroll
        for (int d = 0; d < 16; ++d)
            buf[d] = *reinterpret_cast<const uint2*>(PBbase + (size_t)(pL - 1 - d) * PRB);
        const char* Pc = PBbase + (size_t)(pL - 1 - 16) * PRB;
        v2d cA, cB, nA, nB;
        { H4 h0; h0.u = buf[0]; CVTP(h0, cA, cB); }
        const int nfull = NB >> 4, rem = NB & 15;
        for (int c = 0; c < nfull; ++c) {
            #pragma unroll
            for (int d = 0; d < 16; ++d) {
                H4 hn; hn.u = buf[(d + 1) & 15];
                buf[d] = *reinterpret_cast<const uint2*>(Pc - (size_t)d * PRB);
                CVTP(hn, nA, nB);
                BSTEPV(cB);          // frame tB first (higher t)
                BSTEPV(cA);
                cA = nA; cB = nB;
            }
            RENORMV();
            Pc -= (size_t)16 * PRB;
        }
        #pragma unroll
        for (int d = 0; d < 16; ++d) {
            if (d < rem) {
                H4 h; h.u = buf[d];
                v2d qA, qB; CVTP(h, qA, qB);
                BSTEPV(qB);
                BSTEPV(qA);
            }
        }
        RENORMV();
        // final shift-add (no q): C = betaX at frame 2P
        {
            double b0 = d02.x, b1 = d13.x, b2 = d02.y, b3 = d13.y;
            double bp0 = dpp_shl1_f64(b0);
            double bp1 = dpp_shl1_f64(b1);
            double c0 = b0 + b1;
            double c1 = fma(sk3, b3, b1 + b2);
            double c2 = b2 + b3;
            double c3 = fma(skB, bp1, b3 + bp0);
            SC[sub][4 * lane + 0] = c0; SC[sub][4 * lane + 1] = c1;
            SC[sub][4 * lane + 2] = c2; SC[sub][4 * lane + 3] = c3;
        }
        if (lane == 0) sE[sub][1] = Epow;
    }

    // logSb partial sums over frames 1..n-1, strided across this batch's 128 threads
    double cb = 0.0;
    for (int t = 1 + ltid; t < n; t += 128) cb += (double)logSb[b * TT + t];
    #pragma unroll
    for (int off = 32; off; off >>= 1) cb += __shfl_xor(cb, off);
    if (lane == 0) sred[sub][wv] = cb;

    __syncthreads();

    if (wv == 0) {
        double d0 = SA[sub][4 * lane + 0] * SC[sub][4 * lane + 0]
                  + SA[sub][4 * lane + 1] * SC[sub][4 * lane + 1]
                  + SA[sub][4 * lane + 2] * SC[sub][4 * lane + 2]
                  + SA[sub][4 * lane + 3] * SC[sub][4 * lane + 3];
        #pragma unroll
        for (int off = 32; off; off >>= 1) d0 += __shfl_xor(d0, off);
        if (lane == 0) {
            double dot = d0;
            int extraE = 0;
            long long bits = __double_as_longlong(dot);
            int be = (int)((bits >> 52) & 0x7FF);
            if (be == 0) {                 // denormal rescue
                dot *= 0x1.0p+512;
                bits = __double_as_longlong(dot);
                be = (int)((bits >> 52) & 0x7FF);
                extraE = -512;
            }
            double mant = __longlong_as_double((bits & 0xFFFFFFFFFFFFFLL) | 0x3FF0000000000000LL);
            double logdot = ((double)(be - 1023 + extraE + sE[sub][0] + sE[sub][1])) * LN2D
                          + (double)__logf((float)mant);
            double loss = (sred[sub][0] + sred[sub][1] + lsb0) - logdot;
            atomicAdd(out, (float)loss);
        }
    }
}

extern "C" void kernel_launch(void* const* d_in, const int* in_sizes, int n_in,
                              void* d_out, int out_size, void* d_ws, size_t ws_size,
                              hipStream_t stream)
{
    const float* logits  = (const float*)d_in[0];
    const int* targets   = (const int*)d_in[1];
    const int* in_lens   = (const int*)d_in[2];
    const int* tgt_lens  = (const int*)d_in[3];
    float* out = (float*)d_out;

    ushort* pe2 = (ushort*)d_ws;                                     // 64*1000*448 = 28,672,000 B
    float* logSb = (float*)((char*)d_ws + (size_t)BB * NP * PRB);    // +512,000 B

    ctc_k1<<<BB * NP / 4, 256, 0, stream>>>(logits, targets, in_lens, pe2, logSb, out);
    ctc_k2<<<BB / 4, 512, 0, stream>>>(logits, pe2, logSb, targets, in_lens, tgt_lens, out);
}

// Round 16
// 54.001 us; speedup vs baseline: 1.6605x; 1.6605x over previous
//
#include <hip/hip_runtime.h>
#include <hip/hip_fp16.h>
#include <math.h>

#define BB 64
#define TT 2000
#define VV 128
#define SS 100
#define NP 1000            // row-pairs per batch: pair p holds frames 2p+1, 2p+2
#define PRB 448            // bytes per pair-row: 56 lanes * 8B = exactly 7 cache lines
#define LN2D 0.6931471805599453

typedef double v2d __attribute__((ext_vector_type(2)));

// wave-wide f32 sum via DPP; result uniform via readlane
__device__ __forceinline__ float wave_sum_f32(float v) {
    int t;
    t = __builtin_amdgcn_update_dpp(0, __float_as_int(v), 0x111, 0xF, 0xF, true);  v += __int_as_float(t);
    t = __builtin_amdgcn_update_dpp(0, __float_as_int(v), 0x112, 0xF, 0xF, true);  v += __int_as_float(t);
    t = __builtin_amdgcn_update_dpp(0, __float_as_int(v), 0x114, 0xF, 0xF, true);  v += __int_as_float(t);
    t = __builtin_amdgcn_update_dpp(0, __float_as_int(v), 0x118, 0xF, 0xF, true);  v += __int_as_float(t);
    t = __builtin_amdgcn_update_dpp(0, __float_as_int(v), 0x142, 0xA, 0xF, false); v += __int_as_float(t);
    t = __builtin_amdgcn_update_dpp(0, __float_as_int(v), 0x143, 0xC, 0xF, false); v += __int_as_float(t);
    return __int_as_float(__builtin_amdgcn_readlane(__float_as_int(v), 63));
}

// intra-row (16-lane) prefix sum; lane 15 of each row holds its row's full sum
__device__ __forceinline__ float row_sum_f32(float v) {
    int t;
    t = __builtin_amdgcn_update_dpp(0, __float_as_int(v), 0x111, 0xF, 0xF, true);  v += __int_as_float(t);
    t = __builtin_amdgcn_update_dpp(0, __float_as_int(v), 0x112, 0xF, 0xF, true);  v += __int_as_float(t);
    t = __builtin_amdgcn_update_dpp(0, __float_as_int(v), 0x114, 0xF, 0xF, true);  v += __int_as_float(t);
    t = __builtin_amdgcn_update_dpp(0, __float_as_int(v), 0x118, 0xF, 0xF, true);  v += __int_as_float(t);
    return v;
}

// ---------------- Kernel 1: blank-normalized label probs, 4 frames (2 pairs) per wave ----------------
// Lane group f = lane>>4 owns frame 4w+1+f (16 lanes x 2 float4 = full 512B row).
__global__ __launch_bounds__(256) void ctc_k1(
    const float* __restrict__ logits, const int* __restrict__ targets,
    const int* __restrict__ in_lens, ushort* __restrict__ pe2,
    float* __restrict__ logSb, float* __restrict__ out)
{
    if (blockIdx.x == 0 && threadIdx.x == 0) out[0] = 0.f;   // k1 completes before k2 starts
    const int wv = threadIdx.x >> 6, lane = threadIdx.x & 63;
    const int gp = blockIdx.x * 4 + wv;          // 0 .. BB*500-1
    const int b = gp / 500, w = gp - b * 500;
    const int n = in_lens[b];
    const int pL = (n - 2) >> 1;
    const int p0 = 2 * w;
    if (p0 > pL) return;                         // both pairs dead (never consumed)

    const int f  = lane >> 4;                    // frame slot 0..3 within this wave
    const int tF = 4 * w + 1 + f;
    const int trow = (tF < TT) ? tF : (TT - 1);  // clamp: dup row, dead slots only
    const float4* R = reinterpret_cast<const float4*>(logits + ((size_t)b * TT + trow) * VV);
    const int sub16 = lane & 15;
    float4 xa = R[sub16 * 2];
    float4 xb = R[sub16 * 2 + 1];

    float e0 = __expf(xa.x), e1 = __expf(xa.y), e2 = __expf(xa.z), e3 = __expf(xa.w);
    float e4 = __expf(xb.x), e5 = __expf(xb.y), e6 = __expf(xb.z), e7 = __expf(xb.w);
    float sv = row_sum_f32(((e0 + e1) + (e2 + e3)) + ((e4 + e5) + (e6 + e7)));

    __shared__ float sm[4][4][VV];
    {
        float4 ev; ev.x = e0; ev.y = e1; ev.z = e2; ev.w = e3;
        *reinterpret_cast<float4*>(&sm[wv][f][sub16 * 8]) = ev;
        ev.x = e4; ev.y = e5; ev.z = e6; ev.w = e7;
        *reinterpret_cast<float4*>(&sm[wv][f][sub16 * 8 + 4]) = ev;
    }
    // producer and consumer are the SAME wave: no barrier needed

    int tg0 = 0, tg1 = 0;
    if (lane < 50) {
        int2 tg = reinterpret_cast<const int2*>(targets)[b * (SS / 2) + lane];
        tg0 = tg.x; tg1 = tg.y;
    }
    float q1[4], q3[4];
    #pragma unroll
    for (int r = 0; r < 4; ++r) { q1[r] = 0.f; q3[r] = 0.f; }
    if (lane < 50) {
        #pragma unroll
        for (int r = 0; r < 4; ++r) {
            float qi = 1.0f / sm[wv][r][0];
            q1[r] = fminf(sm[wv][r][tg0] * qi, 65504.f);
            q3[r] = fminf(sm[wv][r][tg1] * qi, 65504.f);
        }
    }
    if (lane < 56) {                              // two full 7-line rows, zero padded
        char* dst = (char*)pe2 + ((size_t)b * NP + p0) * PRB + lane * 8;
        ushort4 wA, wB;
        wA.x = __half_as_ushort(__float2half_rn(q1[0]));
        wA.y = __half_as_ushort(__float2half_rn(q3[0]));
        wA.z = __half_as_ushort(__float2half_rn(q1[1]));
        wA.w = __half_as_ushort(__float2half_rn(q3[1]));
        wB.x = __half_as_ushort(__float2half_rn(q1[2]));
        wB.y = __half_as_ushort(__float2half_rn(q3[2]));
        wB.z = __half_as_ushort(__float2half_rn(q1[3]));
        wB.w = __half_as_ushort(__float2half_rn(q3[3]));
        *reinterpret_cast<ushort4*>(dst) = wA;
        *reinterpret_cast<ushort4*>(dst + PRB) = wB;
    }
    if (sub16 == 15 && tF < TT) {                 // one writer lane per frame
        // logSb = log(sum exp x) - x_blank = log(sum / e_blank)   (e_blank = exp(x_blank))
        logSb[b * TT + tF] = __logf(sv / sm[wv][f][0]);
    }
}

// ---------------- Kernel 2: bidirectional scan, 2 waves per batch, packed-f64 (round-14, 38.7us) ----------------
union H4 { uint2 u; __half h[4]; };

__device__ __forceinline__ double dpp_shr1_f64(double x) {   // lane l <- l-1, lane0 -> 0
    long long bl = __double_as_longlong(x);
    int lo = (int)bl, hi = (int)(bl >> 32);
    lo = __builtin_amdgcn_update_dpp(0, lo, 0x138, 0xF, 0xF, true);  // wave_shr:1
    hi = __builtin_amdgcn_update_dpp(0, hi, 0x138, 0xF, 0xF, true);
    return __longlong_as_double((long long)(((unsigned long long)(unsigned)hi << 32) | (unsigned)lo));
}

__device__ __forceinline__ double dpp_shl1_f64(double x) {   // lane l <- l+1, lane63 -> 0
    long long bl = __double_as_longlong(x);
    int lo = (int)bl, hi = (int)(bl >> 32);
    lo = __builtin_amdgcn_update_dpp(0, lo, 0x130, 0xF, 0xF, true);  // wave_shl:1
    hi = __builtin_amdgcn_update_dpp(0, hi, 0x130, 0xF, 0xF, true);
    return __longlong_as_double((long long)(((unsigned long long)(unsigned)hi << 32) | (unsigned)lo));
}

__device__ __forceinline__ int wave_max_i32(int v) {
    int t;
    t = __builtin_amdgcn_update_dpp(0, v, 0x111, 0xF, 0xF, true); v = v > t ? v : t;
    t = __builtin_amdgcn_update_dpp(0, v, 0x112, 0xF, 0xF, true); v = v > t ? v : t;
    t = __builtin_amdgcn_update_dpp(0, v, 0x114, 0xF, 0xF, true); v = v > t ? v : t;
    t = __builtin_amdgcn_update_dpp(0, v, 0x118, 0xF, 0xF, true); v = v > t ? v : t;
    t = __builtin_amdgcn_update_dpp(v, v, 0x142, 0xA, 0xF, false); v = v > t ? v : t;
    t = __builtin_amdgcn_update_dpp(v, v, 0x143, 0xC, 0xF, false); v = v > t ? v : t;
    return __builtin_amdgcn_readlane(v, 63);
}

// state d02=(a0,a2), d13=(a1,a3); per frame: 4 packed f64 ops + 1 f64 DPP shift.
#define FSTEPV(QV) do {                                      \
    double am1 = dpp_shr1_f64(d13.y);                        \
    v2d m; m.x = am1; m.y = d13.x;                           \
    v2d t = d02 + d13;            /* (a0+a1, a2+a3) */       \
    v2d u = skv * m + t;          /* (+sk1*am1, +sk3*a1) */  \
    d02 = d02 + m;                /* (a0+am1, a1+a2) */      \
    d13 = u * (QV);                                          \
} while (0)

// bwd state d02=(b0,b2), d13=(b1,b3)
#define BSTEPV(QV) do {                                      \
    double bp0 = dpp_shl1_f64(d02.x);                        \
    double bp1 = dpp_shl1_f64(d13.x);                        \
    v2d s2; s2.x = d02.y; s2.y = bp0;                        \
    v2d m;  m.x = d13.y;  m.y = bp1;                         \
    v2d t = d13 + s2;             /* (b1+b2, b3+bp0) */      \
    v2d u = skvB * m + t;         /* (+sk3*b3, +skB*bp1) */  \
    d02 = d02 + d13;              /* (b0+b1, b2+b3) */       \
    d13 = u * (QV);                                          \
} while (0)

#define RENORMV() do {                                       \
    int h0 = (int)(__double_as_longlong(d02.x) >> 32);       \
    int h1 = (int)(__double_as_longlong(d13.x) >> 32);       \
    int h2 = (int)(__double_as_longlong(d02.y) >> 32);       \
    int h3 = (int)(__double_as_longlong(d13.y) >> 32);       \
    int m01 = h0 > h1 ? h0 : h1;                             \
    int m23 = h2 > h3 ? h2 : h3;                             \
    int mm  = wave_max_i32(m01 > m23 ? m01 : m23);           \
    int ex  = (mm >> 20) & 0x7FF;                            \
    int exc = ex > 0 ? ex : 1;                               \
    double f = __longlong_as_double((long long)(2046 - exc) << 52); \
    v2d fv; fv.x = f; fv.y = f;                              \
    d02 *= fv; d13 *= fv;                                    \
    Epow += exc - 1023;                                      \
} while (0)

#define CVTP(H, QA, QB) do {                                 \
    (QA).x = (double)__half2float((H).h[0]);                 \
    (QA).y = (double)__half2float((H).h[1]);                 \
    (QB).x = (double)__half2float((H).h[2]);                 \
    (QB).y = (double)__half2float((H).h[3]); } while (0)

__global__ __launch_bounds__(128) void ctc_k2(
    const float* __restrict__ logits, const ushort* __restrict__ pe2,
    const float* __restrict__ logSb, const int* __restrict__ targets,
    const int* __restrict__ in_lens, const int* __restrict__ tgt_lens,
    float* __restrict__ out)
{
    const int b    = blockIdx.x;
    const int tid  = threadIdx.x;
    const int wv   = tid >> 6;          // 0 = forward (alpha), 1 = backward (beta)
    const int lane = tid & 63;
    const int n    = in_lens[b];
    const int tl   = tgt_lens[b];

    const int P  = (13 * (n - 2)) / 50;     // forward pairs (frames 1..2P)
    const int pL = (n - 2) >> 1;            // pair containing frame n-1

    __shared__ double SA[256];
    __shared__ double SC[256];
    __shared__ double sred[2];
    __shared__ int    sE[2];

    int tg0 = 0, tg1 = 0, tgm1 = 0, tg2 = 0;
    if (lane < 50) {
        int2 tg = reinterpret_cast<const int2*>(targets)[b * (SS / 2) + lane];
        tg0 = tg.x; tg1 = tg.y;
    }
    if (lane >= 1 && lane <= 50) tgm1 = targets[b * SS + 2 * lane - 1];
    if (lane <= 48) tg2 = targets[b * SS + 2 * lane + 2];
    const double sk1 = (tg0 != tgm1) ? 1.0 : 0.0;   // fwd: slot 4l+1 <- 4l-1
    const double sk3 = (tg1 != tg0)  ? 1.0 : 0.0;   // fwd: 4l+3 <- 4l+1; bwd: 4l+1 <- 4l+3
    const double skB = (tg2 != tg1)  ? 1.0 : 0.0;   // bwd: slot 4l+3 <- 4l+5
    v2d skv;  skv.x  = sk1; skv.y  = sk3;
    v2d skvB; skvB.x = sk3; skvB.y = skB;

    const int cl = (lane < 51) ? lane : 50;
    const char* PBbase = (const char*)pe2 + (size_t)b * NP * PRB + (size_t)cl * 8;

    v2d d02; d02.x = 0.0; d02.y = 0.0;
    v2d d13; d13.x = 0.0; d13.y = 0.0;
    int Epow = 0;
    double lsb0 = 0.0;
    uint2 buf[16];

    if (wv == 0) {
        // frame-0 prologue from logits
        float2 x0 = reinterpret_cast<const float2*>(logits + (size_t)b * TT * VV)[lane];
        float e00 = __expf(x0.x), e01 = __expf(x0.y);
        float s0v = wave_sum_f32(e00 + e01);
        float qb0 = __shfl(e00, 0);
        int ext1 = targets[b * SS];                      // first label (uniform)
        float qn = __shfl((ext1 & 1) ? e01 : e00, ext1 >> 1);
        if (lane == 0) {
            d02.x = 1.0;
            if (tl > 0) d13.x = (double)qn / (double)qb0;
            lsb0 = (double)__logf(s0v) - (double)x0.x;
        }

        // forward pairs 0 .. P-1 (frames 1..2P), cvt pipelined 1 pair ahead
        #pragma unroll
        for (int d = 0; d < 16; ++d)
            buf[d] = *reinterpret_cast<const uint2*>(PBbase + (size_t)d * PRB);
        const char* Pc = PBbase + (size_t)16 * PRB;
        v2d cA, cB, nA, nB;
        { H4 h0; h0.u = buf[0]; CVTP(h0, cA, cB); }
        const int nfull = P >> 4, rem = P & 15;
        for (int c = 0; c < nfull; ++c) {
            #pragma unroll
            for (int d = 0; d < 16; ++d) {
                H4 hn; hn.u = buf[(d + 1) & 15];
                buf[d] = *reinterpret_cast<const uint2*>(Pc + (size_t)d * PRB);
                CVTP(hn, nA, nB);
                FSTEPV(cA);
                FSTEPV(cB);
                cA = nA; cB = nB;
            }
            RENORMV();
            Pc += (size_t)16 * PRB;
        }
        #pragma unroll
        for (int d = 0; d < 16; ++d) {
            if (d < rem) {
                H4 h; h.u = buf[d];
                v2d qA, qB; CVTP(h, qA, qB);
                FSTEPV(qA);
                FSTEPV(qB);
            }
        }
        RENORMV();
        SA[4 * lane + 0] = d02.x; SA[4 * lane + 1] = d13.x;
        SA[4 * lane + 2] = d02.y; SA[4 * lane + 3] = d13.y;
        if (lane == 0) sE[0] = Epow;
    } else {
        // backward init at frame n-1 (from pair pL)
        H4 hi; hi.u = *reinterpret_cast<const uint2*>(PBbase + (size_t)pL * PRB);
        const bool nOdd = (n & 1);
        double q1i = (double)__half2float(nOdd ? hi.h[2] : hi.h[0]);
        double q3i = (double)__half2float(nOdd ? hi.h[3] : hi.h[1]);
        const int s2i = 2 * tl, s1i = 2 * tl - 1;
        d02.x = (4 * lane     == s2i) ? 1.0 : 0.0;
        d13.x = (4 * lane + 1 == s1i) ? q1i : 0.0;
        d02.y = (4 * lane + 2 == s2i) ? 1.0 : 0.0;
        d13.y = (4 * lane + 3 == s1i) ? q3i : 0.0;
        if (nOdd) {   // extra step for frame n-2 = tA of pair pL
            v2d qv; qv.x = (double)__half2float(hi.h[0]); qv.y = (double)__half2float(hi.h[1]);
            BSTEPV(qv);
        }

        const int NB = pL - P;
        #pragma unroll
        for (int d = 0; d < 16; ++d)
            buf[d] = *reinterpret_cast<const uint2*>(PBbase + (size_t)(pL - 1 - d) * PRB);
        const char* Pc = PBbase + (size_t)(pL - 1 - 16) * PRB;
        v2d cA, cB, nA, nB;
        { H4 h0; h0.u = buf[0]; CVTP(h0, cA, cB); }
        const int nfull = NB >> 4, rem = NB & 15;
        for (int c = 0; c < nfull; ++c) {
            #pragma unroll
            for (int d = 0; d < 16; ++d) {
                H4 hn; hn.u = buf[(d + 1) & 15];
                buf[d] = *reinterpret_cast<const uint2*>(Pc - (size_t)d * PRB);
                CVTP(hn, nA, nB);
                BSTEPV(cB);          // frame tB first (higher t)
                BSTEPV(cA);
                cA = nA; cB = nB;
            }
            RENORMV();
            Pc -= (size_t)16 * PRB;
        }
        #pragma unroll
        for (int d = 0; d < 16; ++d) {
            if (d < rem) {
                H4 h; h.u = buf[d];
                v2d qA, qB; CVTP(h, qA, qB);
                BSTEPV(qB);
                BSTEPV(qA);
            }
        }
        RENORMV();
        // final shift-add (no q): C = betaX at frame 2P
        {
            double b0 = d02.x, b1 = d13.x, b2 = d02.y, b3 = d13.y;
            double bp0 = dpp_shl1_f64(b0);
            double bp1 = dpp_shl1_f64(b1);
            double c0 = b0 + b1;
            double c1 = fma(sk3, b3, b1 + b2);
            double c2 = b2 + b3;
            double c3 = fma(skB, bp1, b3 + bp0);
            SC[4 * lane + 0] = c0; SC[4 * lane + 1] = c1;
            SC[4 * lane + 2] = c2; SC[4 * lane + 3] = c3;
        }
        if (lane == 0) sE[1] = Epow;
    }

    // logSb partial sums over frames 1..n-1, strided across all 128 threads
    double cb = 0.0;
    for (int t = 1 + tid; t < n; t += 128) cb += (double)logSb[b * TT + t];
    #pragma unroll
    for (int off = 32; off; off >>= 1) cb += __shfl_xor(cb, off);
    if (lane == 0) sred[wv] = cb;

    __syncthreads();

    if (wv == 0) {
        double d0 = SA[4 * lane + 0] * SC[4 * lane + 0]
                  + SA[4 * lane + 1] * SC[4 * lane + 1]
                  + SA[4 * lane + 2] * SC[4 * lane + 2]
                  + SA[4 * lane + 3] * SC[4 * lane + 3];
        #pragma unroll
        for (int off = 32; off; off >>= 1) d0 += __shfl_xor(d0, off);
        if (lane == 0) {
            double dot = d0;
            int extraE = 0;
            long long bits = __double_as_longlong(dot);
            int be = (int)((bits >> 52) & 0x7FF);
            if (be == 0) {                 // denormal rescue
                dot *= 0x1.0p+512;
                bits = __double_as_longlong(dot);
                be = (int)((bits >> 52) & 0x7FF);
                extraE = -512;
            }
            double mant = __longlong_as_double((bits & 0xFFFFFFFFFFFFFLL) | 0x3FF0000000000000LL);
            double logdot = ((double)(be - 1023 + extraE + sE[0] + sE[1])) * LN2D
                          + (double)__logf((float)mant);
            double loss = (sred[0] + sred[1] + lsb0) - logdot;
            atomicAdd(out, (float)loss);
        }
    }
}

extern "C" void kernel_launch(void* const* d_in, const int* in_sizes, int n_in,
                              void* d_out, int out_size, void* d_ws, size_t ws_size,
                              hipStream_t stream)
{
    const float* logits  = (const float*)d_in[0];
    const int* targets   = (const int*)d_in[1];
    const int* in_lens   = (const int*)d_in[2];
    const int* tgt_lens  = (const int*)d_in[3];
    float* out = (float*)d_out;

    ushort* pe2 = (ushort*)d_ws;                                     // 64*1000*448 = 28,672,000 B
    float* logSb = (float*)((char*)d_ws + (size_t)BB * NP * PRB);    // +512,000 B

    ctc_k1<<<BB * 500 / 4, 256, 0, stream>>>(logits, targets, in_lens, pe2, logSb, out);
    ctc_k2<<<BB, 128, 0, stream>>>(logits, pe2, logSb, targets, in_lens, tgt_lens, out);
}